// Round 3
// baseline (5538.426 us; speedup 1.0000x reference)
//
#include <hip/hip_runtime.h>
#include <hip/hip_bf16.h>

using bf16 = __hip_bfloat16;
typedef __attribute__((ext_vector_type(8))) short short8;   // 8 bf16 (MFMA A/B frag)
typedef __attribute__((ext_vector_type(4))) float f32x4;    // MFMA C/D frag

#define MFMA16(A, B, C) __builtin_amdgcn_mfma_f32_16x16x32_bf16(A, B, C, 0, 0, 0)

constexpr int Mdim = 512;
constexpr int Ddim = 1024;
constexpr int Hdim = 2048;
constexpr size_t MN = (size_t)Mdim * Ddim;
constexpr int GROUPS = 8;    // independent row-groups (rows evolve independently)
constexpr int GBLK = 32;     // blocks per group
constexpr int GROWS = 64;    // rows per group

constexpr double Hs = 1.0 / 16.0;
// CF[s-1][j]: coefficient (times h) of k_{j+1} in the combination after stage s.
__device__ __constant__ float CFd[6][6] = {
    {float(Hs * 1 / 5.), 0.f, 0.f, 0.f, 0.f, 0.f},
    {float(Hs * 3 / 40.), float(Hs * 9 / 40.), 0.f, 0.f, 0.f, 0.f},
    {float(Hs * 44 / 45.), float(-Hs * 56 / 15.), float(Hs * 32 / 9.), 0.f, 0.f, 0.f},
    {float(Hs * 19372 / 6561.), float(-Hs * 25360 / 2187.), float(Hs * 64448 / 6561.),
     float(-Hs * 212 / 729.), 0.f, 0.f},
    {float(Hs * 9017 / 3168.), float(-Hs * 355 / 33.), float(Hs * 46732 / 5247.),
     float(Hs * 49 / 176.), float(-Hs * 5103 / 18656.), 0.f},
    {float(Hs * 35 / 384.), 0.f, float(Hs * 500 / 1113.), float(Hs * 125 / 192.),
     float(-Hs * 2187 / 6784.), float(Hs * 11 / 84.)},
};

__device__ __forceinline__ float tanh_fast(float x) {
  float xc = fminf(fmaxf(x, -15.0f), 15.0f);
  float t = __expf(2.0f * xc);
  return (t - 1.0f) * __builtin_amdgcn_rcpf(t + 1.0f);
}

__device__ __forceinline__ void gload_lds16(const void* g, void* lds) {
  __builtin_amdgcn_global_load_lds((const __attribute__((address_space(1))) void*)g,
                                   (__attribute__((address_space(3))) void*)lds, 16, 0, 0);
}

// Stage [ROWS][BK] bf16 tile: linear LDS dest (global_load_lds constraint), XOR swizzle
// (involution cs^(r&7) on 16B chunks) applied to the GLOBAL source chunk index.
template <int ROWS, int BK, int NT>
__device__ __forceinline__ void stage_tile(const bf16* __restrict__ src, int ld,
                                           bf16* lds_base, int tid) {
  constexpr int CH = BK / 8;
  constexpr int NCH = ROWS * CH;
#pragma unroll
  for (int q0 = 0; q0 < NCH; q0 += NT) {
    const int q = q0 + tid;
    const int r = q / CH;
    const int cs = q % CH;
    const int cg = cs ^ (r & 7);
    gload_lds16(src + (size_t)r * ld + cg * 8, lds_base + q * 8);
  }
}

template <int BK>
__device__ __forceinline__ short8 lds_frag(const bf16* s, int row, int c) {
  return *(const short8*)(s + row * BK + ((c ^ (row & 7)) << 3));
}

// Group barrier: agent-scope; RMW-poll (atomics execute at the coherence point, so no
// stale-L2 spin risk). Release fence flushes this XCD's L2 (H/A writes -> L3); acquire
// fence invalidates so post-barrier reads see other blocks' data. LDS/VGPR (weights)
// are untouched by cache ops -- that is why residency pays under these fences.
__device__ __forceinline__ void group_barrier(unsigned* cnt, unsigned* gen, unsigned target) {
  __syncthreads();
  if (threadIdx.x == 0) {
    __builtin_amdgcn_fence(__ATOMIC_RELEASE, "agent");
    unsigned prev = __hip_atomic_fetch_add(cnt, 1u, __ATOMIC_RELAXED, __HIP_MEMORY_SCOPE_AGENT);
    if (prev == GBLK - 1) {
      __hip_atomic_store(cnt, 0u, __ATOMIC_RELAXED, __HIP_MEMORY_SCOPE_AGENT);
      __hip_atomic_fetch_add(gen, 1u, __ATOMIC_RELEASE, __HIP_MEMORY_SCOPE_AGENT);
    } else {
      while (__hip_atomic_fetch_add(gen, 0u, __ATOMIC_RELAXED, __HIP_MEMORY_SCOPE_AGENT) <
             target) {
        __builtin_amdgcn_s_sleep(8);
      }
    }
    __builtin_amdgcn_fence(__ATOMIC_ACQUIRE, "agent");
  }
  __syncthreads();
}

// Persistent ODE integrator. block b: group g=b&7 (rows 64g..64g+63), slot s=b>>3.
// LDS: W1-slice [64 cols][1024] bf16 resident (128KB) + A-tile double buffer (2x16KB).
// VGPR: W2-slice as 16 B-frags/thread (K interleaved mod 4 across waves).
// Per stage: G1 (H-tile 64x64, K=1024) -> barrier -> G2 (k-tile 64x32, K=2048, K-split
// across waves + LDS reduce) + RK epilogue -> barrier.
__global__ __launch_bounds__(512, 2) void ode_persistent(
    const bf16* __restrict__ W1t, const bf16* __restrict__ W2t, const float* __restrict__ b1,
    const float* __restrict__ b2, bf16* __restrict__ Abuf, bf16* __restrict__ Hbuf,
    bf16* __restrict__ ks, float* __restrict__ y, unsigned* __restrict__ bars) {
  extern __shared__ char smem[];
  bf16* w1s = (bf16*)smem;                          // [64][1024] swizzled, resident
  bf16* bufs[2] = {(bf16*)(smem + 131072), (bf16*)(smem + 147456)};  // [64][128] each
  float* redbuf = (float*)(smem + 131072);          // aliases bufs (used between syncs)

  const int tid = threadIdx.x;
  const int lane = tid & 63;
  const int wid = tid >> 6;
  const int fr = lane & 15;
  const int kg = lane >> 4;
  const int g = blockIdx.x & 7;
  const int s = blockIdx.x >> 3;
  const int grow = g * GROWS;
  // G1 wave split: 2(M) x 4(N); G2 wave split: 4(K) x 2(N)
  const int wrM = wid >> 2, wnN = wid & 3;
  const int kq = wid & 3, nh = wid >> 2;

  unsigned* cnt = bars + g * 32;
  unsigned* gen = bars + g * 32 + 16;
  unsigned bar_t = 0;

  // ---- preload W1-slice -> LDS (swizzled, same involution as stage_tile) ----
#pragma unroll
  for (int it = 0; it < 16; ++it) {
    int q = it * 512 + tid;
    int r = q >> 7;             // 0..63 (col of H for this block's slice)
    int cs = q & 127;
    int cg = cs ^ (r & 7);
    gload_lds16(W1t + (size_t)(s * 64 + r) * 1024 + cg * 8, w1s + q * 8);
  }
  // ---- preload W2 fragments -> VGPR (16 frags; global kk = 4*t + kq) ----
  const int col2 = s * 32 + nh * 16 + fr;
  short8 w2f[16];
#pragma unroll
  for (int j = 0; j < 16; ++j)
    w2f[j] = *(const short8*)(W2t + (size_t)col2 * 2048 + (4 * j + kq) * 32 + kg * 8);
  asm volatile("s_waitcnt vmcnt(0)" ::: "memory");
  __syncthreads();

  for (int step = 0; step < 16; ++step) {
#pragma unroll 1
    for (int S = 1; S <= 6; ++S) {
      // ================= G1: H[grow..][64s..64s+64] = tanh(A @ W1 + b1) ==========
      {
        f32x4 acc1[2] = {};
        const bf16* srcA = Abuf + (size_t)grow * 1024;
        stage_tile<64, 128, 512>(srcA, 1024, bufs[0], tid);
        asm volatile("s_waitcnt vmcnt(0)" ::: "memory");
        __syncthreads();
#pragma unroll
        for (int t = 0; t < 8; ++t) {
          const int cur = t & 1;
          if (t + 1 < 8) stage_tile<64, 128, 512>(srcA + (t + 1) * 128, 1024, bufs[cur ^ 1], tid);
#pragma unroll
          for (int kk = 0; kk < 4; ++kk) {
            const int cl = kk * 4 + kg;
            short8 bv = lds_frag<1024>(w1s, wnN * 16 + fr, t * 16 + cl);
            short8 a0 = lds_frag<128>(bufs[cur], wrM * 32 + fr, cl);
            short8 a1 = lds_frag<128>(bufs[cur], wrM * 32 + 16 + fr, cl);
            acc1[0] = MFMA16(a0, bv, acc1[0]);
            acc1[1] = MFMA16(a1, bv, acc1[1]);
          }
          asm volatile("s_waitcnt vmcnt(0)" ::: "memory");
          __syncthreads();
        }
        const float bvs = b1[s * 64 + wnN * 16 + fr];
#pragma unroll
        for (int m = 0; m < 2; ++m)
#pragma unroll
          for (int e = 0; e < 4; ++e) {
            int r = wrM * 32 + m * 16 + kg * 4 + e;
            Hbuf[(size_t)(grow + r) * 2048 + s * 64 + wnN * 16 + fr] =
                __float2bfloat16(tanh_fast(acc1[m][e] + bvs));
          }
      }
      group_barrier(cnt, gen, ++bar_t);

      // ========== G2: k[grow..][32s..32s+32] = H @ W2 + b2 ; RK combination =======
      {
        f32x4 acc2[4] = {};
        const bf16* srcH = Hbuf + (size_t)grow * 2048;
        stage_tile<64, 128, 512>(srcH, 2048, bufs[0], tid);
        asm volatile("s_waitcnt vmcnt(0)" ::: "memory");
        __syncthreads();
#pragma unroll
        for (int t = 0; t < 16; ++t) {
          const int cur = t & 1;
          if (t + 1 < 16) stage_tile<64, 128, 512>(srcH + (t + 1) * 128, 2048, bufs[cur ^ 1], tid);
          const int cl = kq * 4 + kg;   // this wave's kk within the staged tile
#pragma unroll
          for (int m = 0; m < 4; ++m) {
            short8 a = lds_frag<128>(bufs[cur], m * 16 + fr, cl);
            acc2[m] = MFMA16(a, w2f[t], acc2[m]);
          }
          asm volatile("s_waitcnt vmcnt(0)" ::: "memory");
          __syncthreads();
        }
        // cross-wave K-reduction (4 partials per 64x16 half): 2 rounds via LDS
        if (kq >= 2) {
          float* b = redbuf + ((kq - 2) * 2 + nh) * (64 * 17);
#pragma unroll
          for (int m = 0; m < 4; ++m)
#pragma unroll
            for (int e = 0; e < 4; ++e) b[(m * 16 + kg * 4 + e) * 17 + fr] = acc2[m][e];
        }
        __syncthreads();
        if (kq < 2) {
          float* b = redbuf + (kq * 2 + nh) * (64 * 17);
#pragma unroll
          for (int m = 0; m < 4; ++m)
#pragma unroll
            for (int e = 0; e < 4; ++e) acc2[m][e] += b[(m * 16 + kg * 4 + e) * 17 + fr];
        }
        __syncthreads();
        if (kq == 1) {
          float* b = redbuf + (4 + nh) * (64 * 17);
#pragma unroll
          for (int m = 0; m < 4; ++m)
#pragma unroll
            for (int e = 0; e < 4; ++e) b[(m * 16 + kg * 4 + e) * 17 + fr] = acc2[m][e];
        }
        __syncthreads();
        if (kq == 0) {
          float* b = redbuf + (4 + nh) * (64 * 17);
          const float bvs = b2[col2];
#pragma unroll
          for (int m = 0; m < 4; ++m)
#pragma unroll
            for (int e = 0; e < 4; ++e) {
              int r = m * 16 + kg * 4 + e;
              size_t idx = (size_t)(grow + r) * 1024 + col2;
              float kv = acc2[m][e] + b[r * 17 + fr] + bvs;
              if (S < 6) ks[(size_t)(S - 1) * MN + idx] = __float2bfloat16(kv);
              float comb = y[idx] + CFd[S - 1][S - 1] * kv;
              for (int j = 0; j + 1 < S; ++j)
                comb += CFd[S - 1][j] * __bfloat162float(ks[(size_t)j * MN + idx]);
              if (S == 6) y[idx] = comb;
              Abuf[idx] = __float2bfloat16(comb);
            }
        }
      }
      group_barrier(cnt, gen, ++bar_t);
    }
  }
}

// fp32 [R][C] -> bf16 [C][R]
__global__ void transpose_to_bf16(const float* __restrict__ in, bf16* __restrict__ out, int R,
                                  int C) {
  __shared__ float t[32][33];
  const int c0 = blockIdx.x * 32, r0 = blockIdx.y * 32;
#pragma unroll
  for (int i = threadIdx.y; i < 32; i += 8)
    t[i][threadIdx.x] = in[(size_t)(r0 + i) * C + c0 + threadIdx.x];
  __syncthreads();
#pragma unroll
  for (int i = threadIdx.y; i < 32; i += 8)
    out[(size_t)(c0 + i) * R + r0 + threadIdx.x] = __float2bfloat16(t[threadIdx.x][i]);
}

__global__ void init_y(const float* __restrict__ x, float* __restrict__ y,
                       bf16* __restrict__ A, int n) {
  int i = blockIdx.x * blockDim.x + threadIdx.x;
  if (i < n) {
    float v = x[i];
    y[i] = v;
    A[i] = __float2bfloat16(v);
  }
}

extern "C" void kernel_launch(void* const* d_in, const int* in_sizes, int n_in, void* d_out,
                              int out_size, void* d_ws, size_t ws_size, hipStream_t stream) {
  const float* x = (const float*)d_in[0];
  const float* W1 = (const float*)d_in[1];
  const float* b1 = (const float*)d_in[2];
  const float* W2 = (const float*)d_in[3];
  const float* b2 = (const float*)d_in[4];
  float* y = (float*)d_out;

  char* ws = (char*)d_ws;
  bf16* W1t = (bf16*)(ws + 0);                 // [2048][1024] bf16, 4 MB
  bf16* W2t = (bf16*)(ws + (4ull << 20));      // [1024][2048] bf16, 4 MB
  bf16* Abuf = (bf16*)(ws + (8ull << 20));     // [512][1024] bf16, 1 MB
  bf16* Hbuf = (bf16*)(ws + (9ull << 20));     // [512][2048] bf16, 2 MB
  bf16* ks = (bf16*)(ws + (11ull << 20));      // 5 x [512][1024] bf16, 5 MB
  unsigned* bars = (unsigned*)(ws + (16ull << 20));  // 8 groups x {cnt,gen}, 1 KB

  static_assert(131072 + 2 * 16384 == 163840, "LDS budget");
  hipFuncSetAttribute((const void*)ode_persistent, hipFuncAttributeMaxDynamicSharedMemorySize,
                      163840);

  transpose_to_bf16<<<dim3(Hdim / 32, Ddim / 32), dim3(32, 8), 0, stream>>>(W1, W1t, Ddim, Hdim);
  transpose_to_bf16<<<dim3(Ddim / 32, Hdim / 32), dim3(32, 8), 0, stream>>>(W2, W2t, Hdim, Ddim);
  init_y<<<(int)(MN / 256), 256, 0, stream>>>(x, y, Abuf, (int)MN);
  hipMemsetAsync(bars, 0, 1024, stream);

  ode_persistent<<<GROUPS * GBLK, 512, 163840, stream>>>(W1t, W2t, b1, b2, Abuf, Hbuf, ks, y,
                                                         bars);
}

// Round 4
// 2044.874 us; speedup vs baseline: 2.7084x; 2.7084x over previous
//
#include <hip/hip_runtime.h>
#include <hip/hip_bf16.h>

using bf16 = __hip_bfloat16;
typedef __attribute__((ext_vector_type(8))) short short8;   // 8 bf16 (MFMA A/B frag)
typedef __attribute__((ext_vector_type(4))) float f32x4;    // MFMA C/D frag

#define MFMA16(A, B, C) __builtin_amdgcn_mfma_f32_16x16x32_bf16(A, B, C, 0, 0, 0)

constexpr int Mdim = 512;
constexpr int Ddim = 1024;
constexpr int Hdim = 2048;
constexpr size_t MN = (size_t)Mdim * Ddim;

constexpr double Hs = 1.0 / 16.0;
// CF[s-1][j]: coefficient (times h) of k_{j+1} in the combination after stage s.
constexpr float CF[6][6] = {
    {float(Hs * 1 / 5.), 0.f, 0.f, 0.f, 0.f, 0.f},
    {float(Hs * 3 / 40.), float(Hs * 9 / 40.), 0.f, 0.f, 0.f, 0.f},
    {float(Hs * 44 / 45.), float(-Hs * 56 / 15.), float(Hs * 32 / 9.), 0.f, 0.f, 0.f},
    {float(Hs * 19372 / 6561.), float(-Hs * 25360 / 2187.), float(Hs * 64448 / 6561.),
     float(-Hs * 212 / 729.), 0.f, 0.f},
    {float(Hs * 9017 / 3168.), float(-Hs * 355 / 33.), float(Hs * 46732 / 5247.),
     float(Hs * 49 / 176.), float(-Hs * 5103 / 18656.), 0.f},
    {float(Hs * 35 / 384.), 0.f, float(Hs * 500 / 1113.), float(Hs * 125 / 192.),
     float(-Hs * 2187 / 6784.), float(Hs * 11 / 84.)},
};

__device__ __forceinline__ float tanh_fast(float x) {
  float xc = fminf(fmaxf(x, -15.0f), 15.0f);
  float t = __expf(2.0f * xc);
  return (t - 1.0f) * __builtin_amdgcn_rcpf(t + 1.0f);
}

__device__ __forceinline__ void gload_lds16(const void* g, void* lds) {
  __builtin_amdgcn_global_load_lds((const __attribute__((address_space(1))) void*)g,
                                   (__attribute__((address_space(3))) void*)lds, 16, 0, 0);
}

// Stage [ROWS][BK] bf16 tile: linear LDS dest (global_load_lds constraint), XOR swizzle
// (involution cs^(r&7) on 16B chunks) applied to the GLOBAL source chunk index.
template <int ROWS, int BK>
__device__ __forceinline__ void stage_tile(const bf16* __restrict__ src, int ld,
                                           bf16* lds_base, int tid) {
  constexpr int CH = BK / 8;
  constexpr int NCH = ROWS * CH;
#pragma unroll
  for (int q0 = 0; q0 < NCH; q0 += 256) {
    const int q = q0 + tid;
    const int r = q / CH;
    const int cs = q % CH;
    const int cg = cs ^ (r & 7);
    gload_lds16(src + (size_t)r * ld + cg * 8, lds_base + q * 8);
  }
}

template <int BK>
__device__ __forceinline__ short8 lds_frag(const bf16* s, int row, int c) {
  return *(const short8*)(s + row * BK + ((c ^ (row & 7)) << 3));
}

// C = A(MxK bf16 rm) * Bt^T (Bt [N][K] bf16 rm); BMxBN tile, 4 waves in 2x2.
// 1D grid of 512 blocks, XCD-swizzled so the 4 n-tiles of one XCD share a weight slice:
//   xcd = bid&7 ; nt = xcd*4 + ((bid>>3)&3) ; mt = bid>>5.   (NT=32 n-tiles, MT=16 m-tiles)
// MODE 0: Hout = bf16(tanh(C + bias))                              (GEMM1)
// MODE 1: k_S = C + bias; store bf16 k_S (S<6); Anext = bf16(y + sum CF*k_j);
//         S==6 additionally writes y (f32, 5th-order update).      (GEMM2 stage S)
template <int MODE, int STAGE, int BM, int BN, int BK>
__global__ __launch_bounds__(256, 2) void fused_gemm(
    const bf16* __restrict__ A, const bf16* __restrict__ Bt, const float* __restrict__ bias,
    int K, int N, bf16* __restrict__ Hout, float* __restrict__ y, bf16* __restrict__ ks,
    bf16* __restrict__ Anext) {
  constexpr int WTM = BM / 2, WTN = BN / 2;
  constexpr int MR = WTM / 16, NR = WTN / 16;
  constexpr int KK = BK / 32;

  __shared__ bf16 sA[2][BM * BK];
  __shared__ bf16 sB[2][BN * BK];

  const int tid = threadIdx.x;
  const int lane = tid & 63;
  const int wid = tid >> 6;
  const int wr = wid >> 1, wc = wid & 1;
  const int fr = lane & 15;
  const int kg = lane >> 4;

  const int bid = blockIdx.x;
  const int nt = (bid & 7) * 4 + ((bid >> 3) & 3);
  const int mt = bid >> 5;
  const int brow = mt * BM;
  const int bcol = nt * BN;
  const bf16* Ablk = A + (size_t)brow * K;
  const bf16* Bblk = Bt + (size_t)bcol * K;

  f32x4 acc[MR][NR][2] = {};   // even/odd-kk accumulator chains (halves MFMA dep stalls)

  const int nt_iters = K / BK;
  stage_tile<BM, BK>(Ablk, K, sA[0], tid);
  stage_tile<BN, BK>(Bblk, K, sB[0], tid);
  asm volatile("s_waitcnt vmcnt(0)" ::: "memory");
  __syncthreads();

  int cur = 0;
  for (int t = 0; t < nt_iters; ++t) {
    if (t + 1 < nt_iters) {
      stage_tile<BM, BK>(Ablk + (t + 1) * BK, K, sA[cur ^ 1], tid);
      stage_tile<BN, BK>(Bblk + (t + 1) * BK, K, sB[cur ^ 1], tid);
    }
    const bf16* sa = sA[cur];
    const bf16* sb = sB[cur];
#pragma unroll
    for (int kk = 0; kk < KK; ++kk) {
      const int c = kk * 4 + kg;
      short8 af[MR], bv[NR];
#pragma unroll
      for (int m = 0; m < MR; ++m) af[m] = lds_frag<BK>(sa, wr * WTM + m * 16 + fr, c);
#pragma unroll
      for (int n = 0; n < NR; ++n) bv[n] = lds_frag<BK>(sb, wc * WTN + n * 16 + fr, c);
#pragma unroll
      for (int m = 0; m < MR; ++m)
#pragma unroll
        for (int n = 0; n < NR; ++n)
          acc[m][n][kk & 1] = MFMA16(af[m], bv[n], acc[m][n][kk & 1]);
    }
    asm volatile("s_waitcnt vmcnt(0)" ::: "memory");
    __syncthreads();
    cur ^= 1;
  }

  // Epilogue. C/D frag layout (m89-verified): col = lane&15, row = (lane>>4)*4 + e.
  const int r0 = brow + wr * WTM + kg * 4;
  const int c0 = bcol + wc * WTN + fr;
#pragma unroll
  for (int m = 0; m < MR; ++m) {
#pragma unroll
    for (int n = 0; n < NR; ++n) {
      const int c = c0 + n * 16;
      const float bvs = bias[c];
#pragma unroll
      for (int e = 0; e < 4; ++e) {
        const int r = r0 + m * 16 + e;
        const size_t idx = (size_t)r * N + c;
        const float cv = acc[m][n][0][e] + acc[m][n][1][e];
        if constexpr (MODE == 0) {
          Hout[idx] = __float2bfloat16(tanh_fast(cv + bvs));
        } else {
          const float kv = cv + bvs;
          if constexpr (STAGE < 6) ks[(size_t)(STAGE - 1) * MN + idx] = __float2bfloat16(kv);
          float comb = y[idx] + CF[STAGE - 1][STAGE - 1] * kv;
          if constexpr (STAGE >= 2 && CF[STAGE - 1][0] != 0.f)
            comb += CF[STAGE - 1][0] * __bfloat162float(ks[0 * MN + idx]);
          if constexpr (STAGE >= 3 && CF[STAGE - 1][1] != 0.f)
            comb += CF[STAGE - 1][1] * __bfloat162float(ks[1 * MN + idx]);
          if constexpr (STAGE >= 4 && CF[STAGE - 1][2] != 0.f)
            comb += CF[STAGE - 1][2] * __bfloat162float(ks[2 * MN + idx]);
          if constexpr (STAGE >= 5 && CF[STAGE - 1][3] != 0.f)
            comb += CF[STAGE - 1][3] * __bfloat162float(ks[3 * MN + idx]);
          if constexpr (STAGE == 6 && CF[STAGE - 1][4] != 0.f)
            comb += CF[STAGE - 1][4] * __bfloat162float(ks[4 * MN + idx]);
          if constexpr (STAGE == 6) y[idx] = comb;
          Anext[idx] = __float2bfloat16(comb);
        }
      }
    }
  }
}

// fp32 [R][C] -> bf16 [C][R]
__global__ void transpose_to_bf16(const float* __restrict__ in, bf16* __restrict__ out, int R,
                                  int C) {
  __shared__ float t[32][33];
  const int c0 = blockIdx.x * 32, r0 = blockIdx.y * 32;
#pragma unroll
  for (int i = threadIdx.y; i < 32; i += 8)
    t[i][threadIdx.x] = in[(size_t)(r0 + i) * C + c0 + threadIdx.x];
  __syncthreads();
#pragma unroll
  for (int i = threadIdx.y; i < 32; i += 8)
    out[(size_t)(c0 + i) * R + r0 + threadIdx.x] = __float2bfloat16(t[threadIdx.x][i]);
}

__global__ void init_y(const float* __restrict__ x, float* __restrict__ y,
                       bf16* __restrict__ A, int n) {
  int i = blockIdx.x * blockDim.x + threadIdx.x;
  if (i < n) {
    float v = x[i];
    y[i] = v;
    A[i] = __float2bfloat16(v);
  }
}

struct Ptrs {
  const float *b1, *b2;
  bf16 *W1t, *W2t, *Abuf, *Hbuf, *ks;
  float* y;
};

// G1: [512,1024] @ W1t[2048,1024] -> H[512,2048]; tiles 32x64, BK=128, grid 512.
static inline void launch_g1(const Ptrs& p, hipStream_t stream) {
  fused_gemm<0, 0, 32, 64, 128><<<512, 256, 0, stream>>>(
      p.Abuf, p.W1t, p.b1, Ddim, Hdim, p.Hbuf, nullptr, nullptr, nullptr);
}
// G2: H[512,2048] @ W2t[1024,2048] -> k[512,1024]; tiles 32x32, BK=256, grid 512.
template <int S>
static inline void launch_g2(const Ptrs& p, hipStream_t stream) {
  fused_gemm<1, S, 32, 32, 256><<<512, 256, 0, stream>>>(
      p.Hbuf, p.W2t, p.b2, Hdim, Ddim, nullptr, p.y, p.ks, p.Abuf);
}

extern "C" void kernel_launch(void* const* d_in, const int* in_sizes, int n_in, void* d_out,
                              int out_size, void* d_ws, size_t ws_size, hipStream_t stream) {
  const float* x = (const float*)d_in[0];
  const float* W1 = (const float*)d_in[1];
  const float* b1 = (const float*)d_in[2];
  const float* W2 = (const float*)d_in[3];
  const float* b2 = (const float*)d_in[4];
  float* y = (float*)d_out;

  char* ws = (char*)d_ws;
  Ptrs p;
  p.b1 = b1;
  p.b2 = b2;
  p.W1t = (bf16*)(ws + 0);               // [2048][1024] bf16, 4 MB
  p.W2t = (bf16*)(ws + (4ull << 20));    // [1024][2048] bf16, 4 MB
  p.Abuf = (bf16*)(ws + (8ull << 20));   // [512][1024] bf16, 1 MB
  p.Hbuf = (bf16*)(ws + (9ull << 20));   // [512][2048] bf16, 2 MB
  p.ks = (bf16*)(ws + (11ull << 20));    // 5 x [512][1024] bf16, 5 MB
  p.y = y;

  transpose_to_bf16<<<dim3(Hdim / 32, Ddim / 32), dim3(32, 8), 0, stream>>>(W1, p.W1t, Ddim, Hdim);
  transpose_to_bf16<<<dim3(Ddim / 32, Hdim / 32), dim3(32, 8), 0, stream>>>(W2, p.W2t, Hdim, Ddim);
  init_y<<<(int)(MN / 256), 256, 0, stream>>>(x, y, p.Abuf, (int)MN);

  for (int step = 0; step < 16; ++step) {
    launch_g1(p, stream); launch_g2<1>(p, stream);
    launch_g1(p, stream); launch_g2<2>(p, stream);
    launch_g1(p, stream); launch_g2<3>(p, stream);
    launch_g1(p, stream); launch_g2<4>(p, stream);
    launch_g1(p, stream); launch_g2<5>(p, stream);
    launch_g1(p, stream); launch_g2<6>(p, stream);
  }
}